// Round 3
// baseline (186.887 us; speedup 1.0000x reference)
//
#include <hip/hip_runtime.h>

#define SRATE 44100.0
#define L_CHUNK 64
#define SAMPLES_PER_CH 2097152
#define CHUNKS_PER_CH 32768           // SAMPLES_PER_CH / L_CHUNK
#define NCH 8
#define TOTAL_CHUNKS 262144
#define CPB 256                       // chunks per block
#define NBLK 1024                     // TOTAL_CHUNKS / CPB
#define BLK_PER_CH 128                // CHUNKS_PER_CH / CPB
#define NWIN 4                        // windows per chunk (L_CHUNK / WIN)
#define WIN 16                        // samples per window (one 64B line)
#define STRIDE 17                     // LDS row stride (floats)

#ifndef M_PI
#define M_PI 3.14159265358979323846
#endif

struct CoefD { double b0, b1, b2, a1, a2; };

__device__ void cascade_step_d(const CoefD* cf, double* s, double x) {
    double u = x;
    #pragma unroll
    for (int i = 0; i < 5; i++) {
        double y   = cf[i].b0 * u + s[2*i];
        double s1n = cf[i].b1 * u - cf[i].a1 * y + s[2*i+1];
        double s2n = cf[i].b2 * u - cf[i].a2 * y;
        s[2*i]   = s1n;
        s[2*i+1] = s2n;
        u = y;
    }
}

// K0: coefficients + fp32 matrix powers.
// mats_f[0..799]     : Pd[d] = A^(64*2^d),    d=0..7  (k1 in-block scan, k3 decomp)
// mats_f[800..1499]  : Qe[e] = A^(16384*2^e), e=0..6  (k2b block-aggregate scan)
__global__ __launch_bounds__(128) void k0_setup(const float* __restrict__ eqp,
                                                float* __restrict__ coef_f,
                                                float* __restrict__ mats_f) {
    __shared__ CoefD cf[5];
    __shared__ double M[100];
    int t = threadIdx.x;

    if (t == 0) {
        for (int i = 0; i < 5; i++) {
            double g  = (double)eqp[i*3 + 0];
            double fc = (double)eqp[i*3 + 1];
            double q  = (double)eqp[i*3 + 2];
            double A  = pow(10.0, g / 40.0);
            double w0 = 2.0 * M_PI * (fc / SRATE);
            double al = sin(w0) / (2.0 * q);
            double c  = cos(w0);
            double b0, b1, b2, a0, a1, a2;
            if (i == 0 || i == 4) {
                double sgn = (i == 4) ? 1.0 : -1.0;
                double sA = sqrt(A);
                b0 = A * ((A + 1.0) + sgn * (A - 1.0) * c + 2.0 * sA * al);
                b1 = -2.0 * sgn * A * ((A - 1.0) + sgn * (A + 1.0) * c);
                b2 = A * ((A + 1.0) + sgn * (A - 1.0) * c - 2.0 * sA * al);
                a0 = (A + 1.0) - sgn * (A - 1.0) * c + 2.0 * sA * al;
                a1 = 2.0 * sgn * ((A - 1.0) - sgn * (A + 1.0) * c);
                a2 = (A + 1.0) - sgn * (A - 1.0) * c - 2.0 * sA * al;
            } else {
                b0 = 1.0 + al * A; b1 = -2.0 * c; b2 = 1.0 - al * A;
                a0 = 1.0 + al / A; a1 = -2.0 * c; a2 = 1.0 - al / A;
            }
            cf[i].b0 = b0 / a0; cf[i].b1 = b1 / a0; cf[i].b2 = b2 / a0;
            cf[i].a1 = a1 / a0; cf[i].a2 = a2 / a0;
            coef_f[i*5 + 0] = (float)(b0 / a0);
            coef_f[i*5 + 1] = (float)(b1 / a0);
            coef_f[i*5 + 2] = (float)(b2 / a0);
            coef_f[i*5 + 3] = (float)(a1 / a0);
            coef_f[i*5 + 4] = (float)(a2 / a0);
        }
    }
    __syncthreads();

    // A: column j = step(e_j, x=0)
    if (t < 10) {
        double s[10];
        for (int k = 0; k < 10; k++) s[k] = (k == t) ? 1.0 : 0.0;
        cascade_step_d(cf, s, 0.0);
        for (int r = 0; r < 10; r++) M[r*10 + t] = s[r];
    }
    __syncthreads();

    // repeated squaring: after k squarings, M = A^(2^k)
    for (int k = 1; k <= 20; k++) {
        double val = 0.0;
        if (t < 100) {
            int r = t / 10, c = t % 10;
            for (int j = 0; j < 10; j++) val += M[r*10 + j] * M[j*10 + c];
        }
        __syncthreads();
        if (t < 100) {
            M[t] = val;
            if (k >= 6 && k <= 13)  mats_f[(k-6)*100 + t]        = (float)val;
            if (k >= 14)            mats_f[800 + (k-14)*100 + t] = (float)val;
        }
        __syncthreads();
    }
}

// K1: per-chunk zero-state cascade + fused in-block KS scan.
// Writes exclusive local prefixes (ibuf, [block][r][thread]) + block aggregate.
__global__ __launch_bounds__(256, 4) void k1_partial(const float* __restrict__ x,
                                                     const float* __restrict__ coef,
                                                     const float* __restrict__ mats_f,
                                                     float* __restrict__ ibuf,
                                                     float* __restrict__ abuf) {
    __shared__ float smem[CPB * STRIDE];   // inb, later reused as scan buf
    __shared__ float Mds[800];
    int t = threadIdx.x, b = blockIdx.x;

    const float4* x4 = (const float4*)x;
    const size_t base4 = (size_t)b * (CPB * L_CHUNK / 4);   // 4096
    const int cb = t >> 2, q = t & 3;

    // prefetch window 0 (4 full 64B lines per 4-lane group)
    float4 rr[4];
    #pragma unroll
    for (int k = 0; k < 4; k++)
        rr[k] = x4[base4 + (size_t)(cb + 64*k) * (L_CHUNK/4) + q];

    for (int i = t; i < 800; i += 256) Mds[i] = mats_f[i];

    float cb0[5], cb1[5], cb2[5], ca1[5], ca2[5];
    #pragma unroll
    for (int i = 0; i < 5; i++) {
        cb0[i] = coef[i*5+0]; cb1[i] = coef[i*5+1]; cb2[i] = coef[i*5+2];
        ca1[i] = coef[i*5+3]; ca2[i] = coef[i*5+4];
    }

    #pragma unroll
    for (int k = 0; k < 4; k++) {
        int o = (cb + 64*k) * STRIDE + q*4;
        smem[o+0] = rr[k].x; smem[o+1] = rr[k].y;
        smem[o+2] = rr[k].z; smem[o+3] = rr[k].w;
    }
    __syncthreads();

    float s[10];
    #pragma unroll
    for (int k = 0; k < 10; k++) s[k] = 0.0f;

    for (int w = 0; w < NWIN; w++) {
        if (w + 1 < NWIN) {
            #pragma unroll
            for (int k = 0; k < 4; k++)
                rr[k] = x4[base4 + (size_t)(cb + 64*k) * (L_CHUNK/4) + (w+1)*4 + q];
        }
        const float* cur = smem + t * STRIDE;
        #pragma unroll
        for (int i = 0; i < WIN; i++) {
            float u = cur[i];
            #pragma unroll
            for (int st = 0; st < 5; st++) {
                float y  = fmaf(cb0[st], u, s[2*st]);
                float t1 = fmaf(cb1[st], u, s[2*st+1]);
                s[2*st+1] = fmaf(-ca2[st], y, cb2[st] * u);
                s[2*st]   = fmaf(-ca1[st], y, t1);
                u = y;
            }
        }
        __syncthreads();
        if (w + 1 < NWIN) {
            #pragma unroll
            for (int k = 0; k < 4; k++) {
                int o = (cb + 64*k) * STRIDE + q*4;
                smem[o+0] = rr[k].x; smem[o+1] = rr[k].y;
                smem[o+2] = rr[k].z; smem[o+3] = rr[k].w;
            }
            __syncthreads();
        }
    }

    // ---- fused Kogge-Stone scan over the block's 256 chunk states ----
    // reuse smem as buf[256][11]
    float v[10];
    #pragma unroll
    for (int r = 0; r < 10; r++) { v[r] = s[r]; smem[t*11 + r] = v[r]; }
    __syncthreads();

    for (int d = 0; d < 8; d++) {
        float nv[10];
        bool act = (t >= (1 << d));
        if (act) {
            int src = t - (1 << d);
            #pragma unroll
            for (int r = 0; r < 10; r++) {
                float acc = v[r];
                #pragma unroll
                for (int k = 0; k < 10; k++)
                    acc = fmaf(Mds[d*100 + r*10 + k], smem[src*11 + k], acc);
                nv[r] = acc;
            }
        }
        __syncthreads();
        if (act) {
            #pragma unroll
            for (int r = 0; r < 10; r++) { v[r] = nv[r]; smem[t*11 + r] = nv[r]; }
        }
        __syncthreads();
    }

    #pragma unroll
    for (int r = 0; r < 10; r++)
        ibuf[(size_t)b * 2560 + r * 256 + t] = (t > 0) ? smem[(t-1)*11 + r] : 0.0f;
    if (t == 255) {
        #pragma unroll
        for (int r = 0; r < 10; r++) abuf[b * 10 + r] = v[r];
    }
}

// K2b: KS scan of the 128 block-aggregates per channel -> exclusive prefixes.
__global__ __launch_bounds__(1024) void k2b_scan(const float* __restrict__ mats_f,
                                                 const float* __restrict__ abuf,
                                                 float* __restrict__ bbuf) {
    __shared__ float Qds[700];
    __shared__ float buf[1024][11];
    int t = threadIdx.x;
    int i = t & (BLK_PER_CH - 1);          // block-in-channel

    for (int k = t; k < 700; k += 1024) Qds[k] = mats_f[800 + k];

    float v[10];
    #pragma unroll
    for (int r = 0; r < 10; r++) { v[r] = abuf[t * 10 + r]; buf[t][r] = v[r]; }
    __syncthreads();

    for (int e = 0; e < 7; e++) {
        float nv[10];
        bool act = (i >= (1 << e));
        if (act) {
            int src = t - (1 << e);
            #pragma unroll
            for (int r = 0; r < 10; r++) {
                float acc = v[r];
                #pragma unroll
                for (int k = 0; k < 10; k++)
                    acc = fmaf(Qds[e*100 + r*10 + k], buf[src][k], acc);
                nv[r] = acc;
            }
        }
        __syncthreads();
        if (act) {
            #pragma unroll
            for (int r = 0; r < 10; r++) { v[r] = nv[r]; buf[t][r] = nv[r]; }
        }
        __syncthreads();
    }
    #pragma unroll
    for (int r = 0; r < 10; r++)
        bbuf[t * 10 + r] = (i > 0) ? buf[t-1][r] : 0.0f;
}

// K3: init = ibuf_local + A^(64t)*bbuf[b], re-run chunk, coalesced stores.
__global__ __launch_bounds__(256, 4) void k3_final(const float* __restrict__ x,
                                                   const float* __restrict__ coef,
                                                   const float* __restrict__ mats_f,
                                                   const float* __restrict__ ibuf,
                                                   const float* __restrict__ bbuf,
                                                   float* __restrict__ out) {
    __shared__ float inb[CPB * STRIDE];
    __shared__ float outb[CPB * STRIDE];
    __shared__ float Mds[800];
    int t = threadIdx.x, b = blockIdx.x;

    const float4* x4 = (const float4*)x;
    float4* o4 = (float4*)out;
    const size_t base4 = (size_t)b * (CPB * L_CHUNK / 4);
    const int cb = t >> 2, q = t & 3;

    float4 rr[4];
    #pragma unroll
    for (int k = 0; k < 4; k++)
        rr[k] = x4[base4 + (size_t)(cb + 64*k) * (L_CHUNK/4) + q];

    for (int i = t; i < 800; i += 256) Mds[i] = mats_f[i];

    float cb0[5], cb1[5], cb2[5], ca1[5], ca2[5];
    #pragma unroll
    for (int i = 0; i < 5; i++) {
        cb0[i] = coef[i*5+0]; cb1[i] = coef[i*5+1]; cb2[i] = coef[i*5+2];
        ca1[i] = coef[i*5+3]; ca2[i] = coef[i*5+4];
    }

    float s[10];
    #pragma unroll
    for (int r = 0; r < 10; r++)
        s[r] = ibuf[(size_t)b * 2560 + r * 256 + t];
    float v[10];
    #pragma unroll
    for (int r = 0; r < 10; r++) v[r] = bbuf[b * 10 + r];

    #pragma unroll
    for (int k = 0; k < 4; k++) {
        int o = (cb + 64*k) * STRIDE + q*4;
        inb[o+0] = rr[k].x; inb[o+1] = rr[k].y;
        inb[o+2] = rr[k].z; inb[o+3] = rr[k].w;
    }
    __syncthreads();   // inb(w0) + Mds ready

    // v = A^(64*t) * v  via binary decomposition
    for (int d = 0; d < 8; d++) {
        float wv[10];
        #pragma unroll
        for (int r = 0; r < 10; r++) {
            float acc = 0.0f;
            #pragma unroll
            for (int k = 0; k < 10; k++)
                acc = fmaf(Mds[d*100 + r*10 + k], v[k], acc);
            wv[r] = acc;
        }
        bool bit = (t >> d) & 1;
        #pragma unroll
        for (int r = 0; r < 10; r++) v[r] = bit ? wv[r] : v[r];
    }
    #pragma unroll
    for (int r = 0; r < 10; r++) s[r] += v[r];

    for (int w = 0; w < NWIN; w++) {
        if (w + 1 < NWIN) {
            #pragma unroll
            for (int k = 0; k < 4; k++)
                rr[k] = x4[base4 + (size_t)(cb + 64*k) * (L_CHUNK/4) + (w+1)*4 + q];
        }
        const float* cur = inb + t * STRIDE;
        float* orow = outb + t * STRIDE;
        #pragma unroll
        for (int i = 0; i < WIN; i++) {
            float u = cur[i];
            #pragma unroll
            for (int st = 0; st < 5; st++) {
                float y  = fmaf(cb0[st], u, s[2*st]);
                float t1 = fmaf(cb1[st], u, s[2*st+1]);
                s[2*st+1] = fmaf(-ca2[st], y, cb2[st] * u);
                s[2*st]   = fmaf(-ca1[st], y, t1);
                u = y;
            }
            orow[i] = u;
        }
        __syncthreads();   // outb complete; inb consumed

        #pragma unroll
        for (int k = 0; k < 4; k++) {
            int o = (cb + 64*k) * STRIDE + q*4;
            float4 ov = make_float4(outb[o+0], outb[o+1], outb[o+2], outb[o+3]);
            o4[base4 + (size_t)(cb + 64*k) * (L_CHUNK/4) + (size_t)w*4 + q] = ov;
        }
        if (w + 1 < NWIN) {
            #pragma unroll
            for (int k = 0; k < 4; k++) {
                int o = (cb + 64*k) * STRIDE + q*4;
                inb[o+0] = rr[k].x; inb[o+1] = rr[k].y;
                inb[o+2] = rr[k].z; inb[o+3] = rr[k].w;
            }
            __syncthreads();
        }
    }
}

extern "C" void kernel_launch(void* const* d_in, const int* in_sizes, int n_in,
                              void* d_out, int out_size, void* d_ws, size_t ws_size,
                              hipStream_t stream) {
    const float* x   = (const float*)d_in[0];
    const float* eqp = (const float*)d_in[1];
    float* out = (float*)d_out;
    char* ws = (char*)d_ws;

    float* coef_f = (float*)ws;                    // 25 floats
    float* mats_f = (float*)(ws + 256);            // 1500 floats
    float* abuf   = (float*)(ws + 8192);           // 1024*10 floats = 40960 B
    float* bbuf   = (float*)(ws + 49152);          // 40960 B
    float* ibuf   = (float*)(ws + 98304);          // 262144*10*4 = 10.49 MB

    hipLaunchKernelGGL(k0_setup, dim3(1), dim3(128), 0, stream, eqp, coef_f, mats_f);
    hipLaunchKernelGGL(k1_partial, dim3(NBLK), dim3(256), 0, stream,
                       x, coef_f, mats_f, ibuf, abuf);
    hipLaunchKernelGGL(k2b_scan, dim3(1), dim3(1024), 0, stream, mats_f, abuf, bbuf);
    hipLaunchKernelGGL(k3_final, dim3(NBLK), dim3(256), 0, stream,
                       x, coef_f, mats_f, ibuf, bbuf, out);
}